// Round 10
// baseline (270.819 us; speedup 1.0000x reference)
//
#include <hip/hip_runtime.h>
#include <math.h>

#define NE 8
#define KDIM 4096
#define PDIM 64
#define NQ 8                  // K split: eighths
#define QK (KDIM / NQ)        // 512 floats per slice
#define LROW (QK + 16)        // padded LDS row stride (floats)
#define EPS_F32 1.1920929e-07f

typedef float f4 __attribute__((ext_vector_type(4)));

// Phase 1: partial logits. Block (group, q) = 16 tokens x K-slice q (512 floats).
// - W slice staged transposed into 17KB LDS once per block (R5-verified pattern)
//   -> NO per-chunk W vmem traffic (kills the TA line-flood that capped R4/R7/R8).
// - Each wave: 4 tokens, ALL 8 x NT loads issued before the staging barrier.
// - q==7 blocks also fold in the 64 prompt dims (R5-verified pattern).
// Grid = 512 groups x 8 slices = 4096 blocks; ~5-8 blocks/CU co-resident.
__global__ __launch_bounds__(256, 6)
void gate_partial(const float* __restrict__ x,
                  const float* __restrict__ prompt,
                  const float* __restrict__ W,
                  float* __restrict__ partials,   // [NQ][tokens][NE]
                  int tokens)
{
    const int tid   = threadIdx.x;
    const int lane  = tid & 63;
    const int wave  = tid >> 6;          // 0..3
    const int group = blockIdx.x >> 3;
    const int q     = blockIdx.x & 7;    // fast index -> slice diversity per CU
    const int tbase = group * 16 + wave * 4;
    const int k0    = q * QK;

    __shared__ float lds_w[NE][LROW];    // 16,896 B
    __shared__ float lds_wp[NE][68];     // prompt W, 2,176 B (q==7 only)

    // ---- issue ALL 8 x loads up front (pure stream, in flight across staging) ----
    const float* xw = x + (size_t)tbase * KDIM + k0 + lane * 4;
    f4 xv[4][2];
#pragma unroll
    for (int t = 0; t < 4; ++t)
#pragma unroll
        for (int c = 0; c < 2; ++c)
            xv[t][c] = __builtin_nontemporal_load(
                (const f4*)(xw + (size_t)t * KDIM + c * 256));

    // ---- stage W slice transposed into LDS: rows [k0,k0+QK) x 8 = 1024 f4 ----
    // (verbatim R5-verified staging formula)
    const float* Wq = W + (size_t)k0 * NE;
#pragma unroll
    for (int it = 0; it < 4; ++it) {
        const int m  = it * 256 + tid;   // f4 index 0..1023
        const f4 v   = *(const f4*)(Wq + 4 * m);
        const int kl = m >> 1;
        const int e0 = (m & 1) * 4;
        lds_w[e0 + 0][kl] = v.x;         // 2-way bank alias: free
        lds_w[e0 + 1][kl] = v.y;
        lds_w[e0 + 2][kl] = v.z;
        lds_w[e0 + 3][kl] = v.w;
    }
    // prompt W rows 4096..4159 x 8 = 128 f4 (q==7 blocks) — verbatim R5
    if (q == 7 && tid < 128) {
        const f4 v   = *(const f4*)(W + (size_t)KDIM * NE + 4 * tid);
        const int kl = tid >> 1;
        const int e0 = (tid & 1) * 4;
        lds_wp[e0 + 0][kl] = v.x;
        lds_wp[e0 + 1][kl] = v.y;
        lds_wp[e0 + 2][kl] = v.z;
        lds_wp[e0 + 3][kl] = v.w;
    }
    __syncthreads();

    float acc[4][NE];
#pragma unroll
    for (int t = 0; t < 4; ++t)
#pragma unroll
        for (int e = 0; e < NE; ++e) acc[t][e] = 0.f;

    // ---- FMA: registers x LDS only (2 chunk-steps of 256 floats) ----
#pragma unroll
    for (int c = 0; c < 2; ++c) {
        const int kl = c * 256 + lane * 4;
#pragma unroll
        for (int eh = 0; eh < 2; ++eh) {      // expert halves cap registers
            f4 wv[4];
#pragma unroll
            for (int j = 0; j < 4; ++j)
                wv[j] = *(const f4*)(&lds_w[eh * 4 + j][kl]);  // conflict-free b128
#pragma unroll
            for (int t = 0; t < 4; ++t)
#pragma unroll
                for (int j = 0; j < 4; ++j) {
                    const int e = eh * 4 + j;
                    acc[t][e] = fmaf(xv[t][c].x, wv[j].x, acc[t][e]);
                    acc[t][e] = fmaf(xv[t][c].y, wv[j].y, acc[t][e]);
                    acc[t][e] = fmaf(xv[t][c].z, wv[j].z, acc[t][e]);
                    acc[t][e] = fmaf(xv[t][c].w, wv[j].w, acc[t][e]);
                }
        }
    }

    // ---- prompt (64 dims) folded into slice 7 — verbatim R5 ----
    if (q == 7 && lane < 16) {
        const int k = lane * 4;
        f4 pv[4];
#pragma unroll
        for (int t = 0; t < 4; ++t)
            pv[t] = *(const f4*)(prompt + (size_t)(tbase + t) * PDIM + k);
#pragma unroll
        for (int eh = 0; eh < 2; ++eh) {
            f4 wv[4];
#pragma unroll
            for (int j = 0; j < 4; ++j)
                wv[j] = *(const f4*)(&lds_wp[eh * 4 + j][k]);
#pragma unroll
            for (int t = 0; t < 4; ++t)
#pragma unroll
                for (int j = 0; j < 4; ++j) {
                    const int e = eh * 4 + j;
                    acc[t][e] = fmaf(pv[t].x, wv[j].x, acc[t][e]);
                    acc[t][e] = fmaf(pv[t].y, wv[j].y, acc[t][e]);
                    acc[t][e] = fmaf(pv[t].z, wv[j].z, acc[t][e]);
                    acc[t][e] = fmaf(pv[t].w, wv[j].w, acc[t][e]);
                }
        }
    }

    // ---- butterfly reduce across the wave — verbatim R5 ----
#pragma unroll
    for (int t = 0; t < 4; ++t)
#pragma unroll
        for (int e = 0; e < NE; ++e) {
            float v = acc[t][e];
#pragma unroll
            for (int off = 32; off >= 1; off >>= 1)
                v += __shfl_xor(v, off, 64);
            acc[t][e] = v;
        }

    // lanes 0..31 write this wave's 4x8 partials, coalesced — verbatim R5
    if (lane < 32) {
        const int t4 = lane >> 3;
        const int e  = lane & 7;
        partials[((size_t)q * tokens + tbase + t4) * NE + e] = acc[t4][e];
    }
}

// Phase 2: combine slices + bias, top-2, softmax, masks & gates — verbatim R5
// (NQ is a parameter). Lane = tt*16 + kk*8 + ee -> one mask element each.
__global__ __launch_bounds__(256)
void gate_epilogue(const float* __restrict__ partials,
                   const float* __restrict__ b,
                   float* __restrict__ out,
                   int tokens)
{
    const int tid   = threadIdx.x;
    const int lane  = tid & 63;
    const int wave  = tid >> 6;
    const int tbase = blockIdx.x * 16 + wave * 4;

    const int tt = lane >> 4;
    const int kk = (lane >> 3) & 1;
    const int ee = lane & 7;
    const int tg = tbase + tt;

    float lg[NE];
#pragma unroll
    for (int e = 0; e < NE; ++e) lg[e] = b[e];
#pragma unroll
    for (int qq = 0; qq < NQ; ++qq) {
        const f4 lo = *(const f4*)(partials + ((size_t)qq * tokens + tg) * NE);
        const f4 hi = *(const f4*)(partials + ((size_t)qq * tokens + tg) * NE + 4);
        lg[0] += lo.x; lg[1] += lo.y; lg[2] += lo.z; lg[3] += lo.w;
        lg[4] += hi.x; lg[5] += hi.y; lg[6] += hi.z; lg[7] += hi.w;
    }

    // top-2, strict > so smallest index wins ties (jax.lax.top_k semantics)
    float v0 = lg[0]; int i0 = 0;
#pragma unroll
    for (int e = 1; e < NE; ++e)
        if (lg[e] > v0) { v0 = lg[e]; i0 = e; }
    float v1 = (i0 == 0) ? lg[1] : lg[0];
    int   i1 = (i0 == 0) ? 1 : 0;
#pragma unroll
    for (int e = 0; e < NE; ++e)
        if (e != i0 && lg[e] > v1) { v1 = lg[e]; i1 = e; }

    float s = 0.f;
#pragma unroll
    for (int e = 0; e < NE; ++e) s += __expf(lg[e] - v0);
    const float g0 = 1.0f / s;
    const float g1 = __expf(v1 - v0) / s;
    const float denom = fmaxf(g0 + g1, EPS_F32);

    const int sel = kk ? i1 : i0;
    out[(size_t)tg * 16 + kk * 8 + ee] = (ee == sel) ? 1.0f : 0.0f;

    if ((lane & 15) < 2) {
        const float g = (ee == 0) ? (g0 / denom) : (g1 / denom);
        out[(size_t)tokens * 16 + (size_t)tg * 2 + ee] = g;
    }
}

extern "C" void kernel_launch(void* const* d_in, const int* in_sizes, int n_in,
                              void* d_out, int out_size, void* d_ws, size_t ws_size,
                              hipStream_t stream) {
    const float* x      = (const float*)d_in[0];
    const float* prompt = (const float*)d_in[1];
    const float* W      = (const float*)d_in[2];
    const float* b      = (const float*)d_in[3];
    float* out          = (float*)d_out;
    float* partials     = (float*)d_ws;           // NQ*tokens*NE*4 = 2 MB

    const int tokens = in_sizes[0] / KDIM;        // 8192

    hipLaunchKernelGGL(gate_partial, dim3((tokens / 16) * NQ), dim3(256), 0, stream,
                       x, prompt, W, partials, tokens);
    hipLaunchKernelGGL(gate_epilogue, dim3(tokens / 16), dim3(256), 0, stream,
                       partials, b, out, tokens);
}